// Round 8
// baseline (739.293 us; speedup 1.0000x reference)
//
#include <hip/hip_runtime.h>
#include <hip/hip_bf16.h>

#define ALPHA 0.2f
#define NEG_INF -9000000000000000.0f

// Problem constants
#define N_NODES 1024
#define F_DIM   128
#define E_EDGES 32768
#define NN      (N_NODES * N_NODES)   // 1048576

typedef float f32x4 __attribute__((ext_vector_type(4)));

// ---------------------------------------------------------------------------
// K1: Wh = h @ W   (1024x128) @ (128x128)
// ---------------------------------------------------------------------------
__global__ __launch_bounds__(256) void k_wh(const float* __restrict__ h,
                                            const float* __restrict__ W,
                                            float* __restrict__ Wh) {
    int idx = blockIdx.x * 256 + threadIdx.x;     // 0 .. 131071
    int i = idx >> 7;
    int f = idx & 127;
    const float* hrow = h + i * 128;
    float acc = 0.f;
#pragma unroll 16
    for (int k = 0; k < 128; ++k)
        acc = fmaf(hrow[k], W[k * 128 + f], acc);
    Wh[idx] = acc;
}

// ---------------------------------------------------------------------------
// K2: s1 = Wh@a1, s2 = Wh@a2 (per node), v3 = W@a3
// blocks 0..1023: s1[i], s2[i].  blocks 1024..1151: v3[row]
// ---------------------------------------------------------------------------
__global__ __launch_bounds__(64) void k_vecs(const float* __restrict__ Wh,
                                             const float* __restrict__ W,
                                             const float* __restrict__ a,
                                             float* __restrict__ s1,
                                             float* __restrict__ s2,
                                             float* __restrict__ v3) {
    int b = blockIdx.x;
    int lane = threadIdx.x;     // 0..63
    if (b < N_NODES) {
        const float* row = Wh + b * 128;
        float x0 = row[lane], x1 = row[lane + 64];
        float p1 = fmaf(x0, a[lane],       x1 * a[lane + 64]);
        float p2 = fmaf(x0, a[128 + lane], x1 * a[192 + lane]);
#pragma unroll
        for (int off = 32; off; off >>= 1) {
            p1 += __shfl_xor(p1, off);
            p2 += __shfl_xor(p2, off);
        }
        if (lane == 0) { s1[b] = p1; s2[b] = p2; }
    } else {
        int i = b - N_NODES;
        const float* row = W + i * 128;
        float p = fmaf(row[lane], a[256 + lane], row[lane + 64] * a[320 + lane]);
#pragma unroll
        for (int off = 32; off; off >>= 1) p += __shfl_xor(p, off);
        if (lane == 0) v3[i] = p;
    }
}

// ---------------------------------------------------------------------------
// K3 (dominant): s3 GEMV over node2node_features (1M x 128, 512 MiB), but
// ONLY for rows where adj>0 (s3 is dead under the mask; ~50% skipped).
// Fused leaky_relu(s1[i]+s2[j]+s3) + mask. Writes emask (1M fp32).
// 32 lanes per row, nontemporal float4 loads, shuffle reduce. 32 rows/block.
// ---------------------------------------------------------------------------
__global__ __launch_bounds__(256) void k_s3(const float* __restrict__ n2n,
                                            const float* __restrict__ v3,
                                            const float* __restrict__ s1,
                                            const float* __restrict__ s2,
                                            const int* __restrict__ adj,
                                            float* __restrict__ emask) {
    int tid  = threadIdx.x;
    int lane = tid & 63;
    int wave = tid >> 6;           // 0..3
    int sub  = lane & 31;          // lane within 32-group
    int half = lane >> 5;          // 0 or 1: which row of the wave's pair

    f32x4 v = ((const f32x4*)v3)[sub];   // 512B, L1-resident broadcast

    long long base = (long long)blockIdx.x * 32;

    // hoist the 4 gate reads so the row-loads can issue independently
    int keep[4];
#pragma unroll
    for (int c = 0; c < 4; ++c)
        keep[c] = adj[base + c * 8 + wave * 2 + half];

#pragma unroll
    for (int c = 0; c < 4; ++c) {
        long long r = base + c * 8 + wave * 2 + half;
        float val = 0.f;
        if (keep[c] > 0) {         // exec-masked: skipped rows fetch nothing
            const f32x4* rowp = (const f32x4*)(n2n + r * 128);
            f32x4 x = __builtin_nontemporal_load(rowp + sub);
            val = fmaf(x.x, v.x, fmaf(x.y, v.y, fmaf(x.z, v.z, x.w * v.w)));
        }
        val += __shfl_xor(val, 16);
        val += __shfl_xor(val, 8);
        val += __shfl_xor(val, 4);
        val += __shfl_xor(val, 2);
        val += __shfl_xor(val, 1);
        if (sub == 0) {
            float o = NEG_INF;
            if (keep[c] > 0) {
                int i = (int)(r >> 10);
                int j = (int)(r & 1023);
                float e = s1[i] + s2[j] + val;
                o = e > 0.f ? e : ALPHA * e;
            }
            __builtin_nontemporal_store(o, emask + r);
        }
    }
}

// ---------------------------------------------------------------------------
// K4: per-row softmax over emask + h_prime = elu(att @ Wh).
// 4 rows per block (256 threads) so each Wh float4 read from L2 is reused 4x.
// ---------------------------------------------------------------------------
#define ROWS_PER_BLK 4
__global__ __launch_bounds__(256) void k_attn(const float* __restrict__ emask,
                                              const float* __restrict__ Wh,
                                              float* __restrict__ out) {
    __shared__ float att[ROWS_PER_BLK][1024];
    __shared__ float red[4];
    __shared__ float4 part[8][32];
    __shared__ float rsum[ROWS_PER_BLK];

    int tid = threadIdx.x;
    int i0 = blockIdx.x * ROWS_PER_BLK;

    // ---- per-row: max, exp, sum ----
    for (int r = 0; r < ROWS_PER_BLK; ++r) {
        const float* erow = emask + (long long)(i0 + r) * 1024;
        float v0 = erow[tid];
        float v1 = erow[tid + 256];
        float v2 = erow[tid + 512];
        float v3r = erow[tid + 768];
        float m = fmaxf(fmaxf(v0, v1), fmaxf(v2, v3r));
#pragma unroll
        for (int off = 32; off; off >>= 1) m = fmaxf(m, __shfl_xor(m, off));
        if ((tid & 63) == 0) red[tid >> 6] = m;
        __syncthreads();
        m = fmaxf(fmaxf(red[0], red[1]), fmaxf(red[2], red[3]));
        __syncthreads();   // red[] free for reuse

        float e0 = expf(v0 - m), e1 = expf(v1 - m), e2 = expf(v2 - m), e3 = expf(v3r - m);
        att[r][tid] = e0; att[r][tid + 256] = e1; att[r][tid + 512] = e2; att[r][tid + 768] = e3;
        float s = e0 + e1 + e2 + e3;
#pragma unroll
        for (int off = 32; off; off >>= 1) s += __shfl_xor(s, off);
        if ((tid & 63) == 0) red[tid >> 6] = s;
        __syncthreads();
        if (tid == 0) rsum[r] = 1.0f / (red[0] + red[1] + red[2] + red[3]);
        __syncthreads();
    }

    // ---- acc[r] = att[r] @ Wh, j split into 8 slices of 128 ----
    int f4 = tid & 31;         // feature float4 group
    int slice = tid >> 5;      // 0..7
    const float4* WhV = (const float4*)Wh;
    float4 acc[ROWS_PER_BLK];
#pragma unroll
    for (int r = 0; r < ROWS_PER_BLK; ++r) acc[r] = make_float4(0.f, 0.f, 0.f, 0.f);
    int jbase = slice * 128;
    for (int jj = 0; jj < 128; ++jj) {
        int j = jbase + jj;
        float4 w = WhV[j * 32 + f4];
#pragma unroll
        for (int r = 0; r < ROWS_PER_BLK; ++r) {
            float aw = att[r][j];
            acc[r].x = fmaf(aw, w.x, acc[r].x);
            acc[r].y = fmaf(aw, w.y, acc[r].y);
            acc[r].z = fmaf(aw, w.z, acc[r].z);
            acc[r].w = fmaf(aw, w.w, acc[r].w);
        }
    }

    // ---- reduce 8 slices per row, apply 1/sum and ELU, store ----
    for (int r = 0; r < ROWS_PER_BLK; ++r) {
        part[slice][f4] = acc[r];
        __syncthreads();
        if (tid < 32) {
            float4 t = part[0][tid];
#pragma unroll
            for (int sl = 1; sl < 8; ++sl) {
                float4 p = part[sl][tid];
                t.x += p.x; t.y += p.y; t.z += p.z; t.w += p.w;
            }
            float rs = rsum[r];
            t.x *= rs; t.y *= rs; t.z *= rs; t.w *= rs;
            t.x = t.x > 0.f ? t.x : expm1f(t.x);
            t.y = t.y > 0.f ? t.y : expm1f(t.y);
            t.z = t.z > 0.f ? t.z : expm1f(t.z);
            t.w = t.w > 0.f ? t.w : expm1f(t.w);
            ((float4*)(out + (long long)(i0 + r) * 128))[tid] = t;
        }
        __syncthreads();
    }
}

// ---------------------------------------------------------------------------
// K5: edge_out = elu(edge_attr @ W), 32768x128. 64 rows/block, W + rows in LDS.
// ---------------------------------------------------------------------------
__global__ __launch_bounds__(256) void k_edge(const float* __restrict__ ea,
                                              const float* __restrict__ W,
                                              float* __restrict__ out) {
    __shared__ float Wlds[128 * 128];   // 64 KB
    __shared__ float elds[64 * 128];    // 32 KB
    int tid = threadIdx.x;

    {
        const float4* Wv = (const float4*)W;
        float4* Wl = (float4*)Wlds;
#pragma unroll
        for (int t = tid; t < 4096; t += 256) Wl[t] = Wv[t];
        long long rowbase = (long long)blockIdx.x * 64;
        const float4* ev = (const float4*)(ea + rowbase * 128);
        float4* el = (float4*)elds;
#pragma unroll
        for (int t = tid; t < 2048; t += 256) el[t] = ev[t];
    }
    __syncthreads();

    int f4 = tid & 31;     // features f4*4 .. +3
    int rg = tid >> 5;     // 0..7 -> rows rg*8 .. +7
    float4 acc[8];
#pragma unroll
    for (int r = 0; r < 8; ++r) acc[r] = make_float4(0.f, 0.f, 0.f, 0.f);

    for (int k4 = 0; k4 < 32; ++k4) {
        float4 w0 = *(const float4*)&Wlds[(k4 * 4 + 0) * 128 + f4 * 4];
        float4 w1 = *(const float4*)&Wlds[(k4 * 4 + 1) * 128 + f4 * 4];
        float4 w2 = *(const float4*)&Wlds[(k4 * 4 + 2) * 128 + f4 * 4];
        float4 w3 = *(const float4*)&Wlds[(k4 * 4 + 3) * 128 + f4 * 4];
#pragma unroll
        for (int r = 0; r < 8; ++r) {
            float4 e4 = *(const float4*)&elds[(rg * 8 + r) * 128 + k4 * 4];
            acc[r].x = fmaf(e4.x, w0.x, fmaf(e4.y, w1.x, fmaf(e4.z, w2.x, fmaf(e4.w, w3.x, acc[r].x))));
            acc[r].y = fmaf(e4.x, w0.y, fmaf(e4.y, w1.y, fmaf(e4.z, w2.y, fmaf(e4.w, w3.y, acc[r].y))));
            acc[r].z = fmaf(e4.x, w0.z, fmaf(e4.y, w1.z, fmaf(e4.z, w2.z, fmaf(e4.w, w3.z, acc[r].z))));
            acc[r].w = fmaf(e4.x, w0.w, fmaf(e4.y, w1.w, fmaf(e4.z, w2.w, fmaf(e4.w, w3.w, acc[r].w))));
        }
    }

    long long rowbase = (long long)blockIdx.x * 64 + rg * 8;
#pragma unroll
    for (int r = 0; r < 8; ++r) {
        float4 t = acc[r];
        t.x = t.x > 0.f ? t.x : expm1f(t.x);
        t.y = t.y > 0.f ? t.y : expm1f(t.y);
        t.z = t.z > 0.f ? t.z : expm1f(t.z);
        t.w = t.w > 0.f ? t.w : expm1f(t.w);
        *(float4*)&out[(long long)N_NODES * F_DIM + (rowbase + r) * 128 + f4 * 4] = t;
    }
}

// ---------------------------------------------------------------------------
extern "C" void kernel_launch(void* const* d_in, const int* in_sizes, int n_in,
                              void* d_out, int out_size, void* d_ws, size_t ws_size,
                              hipStream_t stream) {
    const float* h   = (const float*)d_in[0];
    const float* ea  = (const float*)d_in[1];
    const int*   adj = (const int*)d_in[2];
    const float* n2n = (const float*)d_in[3];
    const float* W   = (const float*)d_in[4];
    const float* a   = (const float*)d_in[5];
    float* out = (float*)d_out;

    float* ws = (float*)d_ws;
    float* Wh    = ws;                  // 131072
    float* s1    = Wh + 131072;         // 1024
    float* s2    = s1 + 1024;           // 1024
    float* v3    = s2 + 1024;           // 128
    float* emask = v3 + 128;            // 1048576  (total ~4.5 MB)

    k_wh  <<<512,  256, 0, stream>>>(h, W, Wh);
    k_vecs<<<1152, 64,  0, stream>>>(Wh, W, a, s1, s2, v3);
    k_s3  <<<NN / 32, 256, 0, stream>>>(n2n, v3, s1, s2, adj, emask);
    k_attn<<<N_NODES / ROWS_PER_BLK, 256, 0, stream>>>(emask, Wh, out);
    k_edge<<<E_EDGES / 64, 256, 0, stream>>>(ea, W, out);
}